// Round 1
// baseline (987.073 us; speedup 1.0000x reference)
//
#include <hip/hip_runtime.h>

// SpectralConv2d as 5 bf16-MFMA GEMM stages + table builds + 2 transposes.
// B=16, Ci=Co=64, S=256, m1=m2=32 -> 63x32 retained modes.

typedef __attribute__((ext_vector_type(8))) short bfrag8;   // 8 bf16 = 16B
typedef __attribute__((ext_vector_type(4))) float facc4;    // MFMA accumulator

// ---- workspace layout (bf16-element offsets) ----
#define F1F_O 0u            // [8 ks][4 nt][64 lane][8 j]        16384
#define T2F_O 16384u        // [8 mt][16 ks][64][8]              65536
#define T4F_O 81920u        // [32 mt][4 ks][64][8]              65536
#define F5F_O 147456u       // [2 ks][16 nt][64][8]              16384
#define WF_O  163840u       // [2016 mode][4 ks][8 nt][64][8]    33030144
#define X1T_O 33193984u     // [1024 bi][32 n][512 kk]           16777216
#define C2_O  49971200u     // [1024 bi][128 m][32 n]            4194304
#define X2M_O 54165504u     // [2016 mode][16 b][128 ic]         4128768
// overlays (stream-ordered lifetimes):
#define Y1_O  WF_O                    // [1024 bo][512 m][32 n] after s3
#define C3_O  X1T_O                   // [2016 mode][16 b][128 nc] after s2
#define X3T_O (X1T_O + 4128768u)      // [1024 bo][32 kx][128 kk]

#define TWO_PI_256 0.0245436926f

__device__ __forceinline__ unsigned short f2bf(float f) {
  unsigned u = __float_as_uint(f);
  u += 0x7fffu + ((u >> 16) & 1u);          // RNE
  return (unsigned short)(u >> 16);
}
__device__ __forceinline__ bfrag8 ldf(const unsigned short* p) {
  return *(const bfrag8*)p;
}

// ---------- build constant DFT matrices in fragment-linear layout ----------
__global__ void k_tables(unsigned short* ws) {
  int t = threadIdx.x;
  for (int q = 0; q < 4; ++q) {
    int idx = blockIdx.x * 1024 + q * 256 + t;
    float val = 0.f; unsigned dst;
    if (idx < 16384) {                       // F1f: B[k=x][n], fwd row rDFT, /256
      int u = idx, j = u & 7, lane = (u >> 3) & 63, nt = (u >> 9) & 3, ks = u >> 11;
      int k = ks * 32 + (lane >> 4) * 8 + j, n = nt * 16 + (lane & 15);
      if (n < 32) val =  cosf((float)((k * n) & 255) * TWO_PI_256) * (1.f / 256.f);
      else        val = -sinf((float)((k * (n - 32)) & 255) * TWO_PI_256) * (1.f / 256.f);
      dst = F1F_O + (unsigned)idx;
    } else if (idx < 81920) {                // T2f: A[m][kk], fwd col DFT (real form)
      int u = idx - 16384, j = u & 7, lane = (u >> 3) & 63, ks = (u >> 9) & 15, mt = u >> 13;
      int m = mt * 16 + (lane & 15), k = ks * 32 + (lane >> 4) * 8 + j;
      if (m < 126) {
        int ky = m < 63 ? m : m - 63;
        int y = k & 255, f = (ky + 225) & 255;
        float ang = (float)((y * f) & 255) * TWO_PI_256;
        float c = cosf(ang), s = sinf(ang);
        val = (m < 63) ? ((k < 256) ? c : s) : ((k < 256) ? -s : c);
      }
      dst = T2F_O + (unsigned)u;
    } else if (idx < 147456) {               // T4f: A[m][kk], inv col DFT
      int u = idx - 81920, j = u & 7, lane = (u >> 3) & 63, ks = (u >> 9) & 3, mt = u >> 11;
      int m = mt * 16 + (lane & 15), k = ks * 32 + (lane >> 4) * 8 + j;
      if (k < 126) {
        int ky = k < 63 ? k : k - 63;
        int y = m & 255, f = (ky + 225) & 255;
        float ang = (float)((y * f) & 255) * TWO_PI_256;
        float c = cosf(ang), s = sinf(ang);
        val = (m < 256) ? ((k < 63) ? c : -s) : ((k < 63) ? s : c);
      }
      dst = T4F_O + (unsigned)u;
    } else {                                 // F5f: B[k][n=x], inv row irDFT, /256
      int u = idx - 147456, j = u & 7, lane = (u >> 3) & 63, nt = (u >> 9) & 15, ks = u >> 13;
      int k = ks * 32 + (lane >> 4) * 8 + j, n = nt * 16 + (lane & 15);
      int kf = k & 31;
      float ang = (float)((kf * n) & 255) * TWO_PI_256;
      if (k < 32) val = ((kf == 0) ? 1.f : 2.f) * cosf(ang) * (1.f / 256.f);
      else        val = (kf == 0) ? 0.f : -2.f * sinf(ang) * (1.f / 256.f);
      dst = F5F_O + (unsigned)u;
    }
    ws[dst] = f2bf(val);
  }
}

// ---------- build per-mode 128x128 real-form weight matrices (frag-linear) ----------
__global__ void k_wf(const float* __restrict__ y0r, const float* __restrict__ y0i,
                     const float* __restrict__ ypr, const float* __restrict__ ypi,
                     const float* __restrict__ w00, unsigned short* ws) {
  unsigned short* Wf = ws + WF_O;
  int mode = blockIdx.x, ky = mode >> 5, kx = mode & 31;
  int t = threadIdx.x;
  for (int c = 0; c < 8; ++c) {
    int ubase = c * 2048 + t * 8;
    int hi = ubase >> 3;                       // = c*256 + t
    int lane = hi & 63, nt = (hi >> 6) & 7, ks = hi >> 9;
    int quad = lane >> 4, nlo = lane & 15;
    int n = nt * 16 + nlo, o = n & 63, oh = n >> 6;
    unsigned short outv[8];
#pragma unroll
    for (int j = 0; j < 8; ++j) {
      int k = ks * 32 + quad * 8 + j;
      int i = k & 63, kh = k >> 6;
      float wr, wi;
      if (kx == 0) {
        if (ky < 31)       { int yi = (i * 64 + o) * 31 + ky;        wr = y0r[yi]; wi = y0i[yi]; }
        else if (ky == 31) { wr = w00[i * 64 + o]; wi = 0.f; }
        else               { int yi = (i * 64 + o) * 31 + (62 - ky); wr = y0r[yi]; wi = -y0i[yi]; }
      } else {
        int yi = ((i * 64 + o) * 63 + ky) * 31 + (kx - 1);
        wr = ypr[yi]; wi = ypi[yi];
      }
      float v = (kh == 0) ? ((oh == 0) ? wr : wi) : ((oh == 0) ? -wi : wr);
      outv[j] = f2bf(v);
    }
    *(uint4*)(Wf + (unsigned)mode * 16384u + ubase) = *(uint4*)outv;
  }
}

// ---------- stage 1: row rDFT.  C1 = bf16(x) (128x256) * F1 (256x64) -> X1t ----------
__global__ void k_s1(const float* __restrict__ x, unsigned short* ws) {
  __shared__ unsigned short F1s[16384];
  __shared__ unsigned short As[128 * 40];     // pad 32->40 (16B-aligned rows, conflict-free)
  const unsigned short* F1g = ws + F1F_O;
  unsigned short* X1t = ws + X1T_O;
  int t = threadIdx.x;
  int bi = blockIdx.x >> 1, y0 = (blockIdx.x & 1) * 128;
#pragma unroll
  for (int q = 0; q < 8; ++q)
    ((uint4*)F1s)[q * 256 + t] = ((const uint4*)F1g)[q * 256 + t];
  int lane = t & 63, w = t >> 6, quad = lane >> 4, nlo = lane & 15;
  int mt0 = w * 2;
  facc4 acc[2][4];
#pragma unroll
  for (int a = 0; a < 2; ++a)
#pragma unroll
    for (int b = 0; b < 4; ++b) acc[a][b] = (facc4){0.f, 0.f, 0.f, 0.f};
  const float* img = x + (size_t)bi * 65536 + (size_t)y0 * 256;
  for (int ks = 0; ks < 8; ++ks) {
    __syncthreads();
#pragma unroll
    for (int q = 0; q < 4; ++q) {             // stage 128x32 fp32 -> bf16 LDS
      int flat = q * 1024 + t * 4;
      int r = flat >> 5, cc = flat & 31;
      float4 v = *(const float4*)(img + r * 256 + ks * 32 + cc);
      unsigned short b4[4] = { f2bf(v.x), f2bf(v.y), f2bf(v.z), f2bf(v.w) };
      *(uint2*)(As + r * 40 + cc) = *(uint2*)b4;
    }
    __syncthreads();
    bfrag8 a0 = *(bfrag8*)(As + (mt0 * 16 + nlo) * 40 + quad * 8);
    bfrag8 a1 = *(bfrag8*)(As + ((mt0 + 1) * 16 + nlo) * 40 + quad * 8);
#pragma unroll
    for (int nt = 0; nt < 4; ++nt) {
      bfrag8 b = *(bfrag8*)(F1s + ((ks * 4 + nt) * 64 + lane) * 8);
      acc[0][nt] = __builtin_amdgcn_mfma_f32_16x16x32_bf16(a0, b, acc[0][nt], 0, 0, 0);
      acc[1][nt] = __builtin_amdgcn_mfma_f32_16x16x32_bf16(a1, b, acc[1][nt], 0, 0, 0);
    }
  }
#pragma unroll
  for (int ml = 0; ml < 2; ++ml)
#pragma unroll
    for (int nt = 0; nt < 4; ++nt) {
      facc4 v = acc[ml][nt];
      int ccol = nt * 16 + nlo, n = ccol & 31, half = ccol >> 5;
      int yrow = y0 + (mt0 + ml) * 16 + quad * 4;
      unsigned short pk[4] = { f2bf(v[0]), f2bf(v[1]), f2bf(v[2]), f2bf(v[3]) };
      *(uint2*)(X1t + (unsigned)bi * 16384u + n * 512 + half * 256 + yrow) = *(uint2*)pk;
    }
}

// ---------- stage 2: col DFT.  C2 = T2 (128x512) * X1t[bi] (512x32) ----------
__global__ void k_s2(unsigned short* ws) {
  const unsigned short* T2f = ws + T2F_O;
  const unsigned short* X1t = ws + X1T_O;
  unsigned short* C2 = ws + C2_O;
  int t = threadIdx.x, lane = t & 63, w = t >> 6, quad = lane >> 4, nlo = lane & 15;
  int bi = blockIdx.x, mt0 = w * 2;
  facc4 acc[2][2];
#pragma unroll
  for (int a = 0; a < 2; ++a)
#pragma unroll
    for (int b = 0; b < 2; ++b) acc[a][b] = (facc4){0.f, 0.f, 0.f, 0.f};
  const unsigned short* Bb = X1t + (unsigned)bi * 16384u;
  for (int ks = 0; ks < 16; ++ks) {
    bfrag8 a0 = ldf(T2f + ((mt0 * 16 + ks) * 64 + lane) * 8);
    bfrag8 a1 = ldf(T2f + (((mt0 + 1) * 16 + ks) * 64 + lane) * 8);
    bfrag8 b0 = ldf(Bb + nlo * 512 + ks * 32 + quad * 8);
    bfrag8 b1 = ldf(Bb + (16 + nlo) * 512 + ks * 32 + quad * 8);
    acc[0][0] = __builtin_amdgcn_mfma_f32_16x16x32_bf16(a0, b0, acc[0][0], 0, 0, 0);
    acc[0][1] = __builtin_amdgcn_mfma_f32_16x16x32_bf16(a0, b1, acc[0][1], 0, 0, 0);
    acc[1][0] = __builtin_amdgcn_mfma_f32_16x16x32_bf16(a1, b0, acc[1][0], 0, 0, 0);
    acc[1][1] = __builtin_amdgcn_mfma_f32_16x16x32_bf16(a1, b1, acc[1][1], 0, 0, 0);
  }
#pragma unroll
  for (int ml = 0; ml < 2; ++ml)
#pragma unroll
    for (int nt = 0; nt < 2; ++nt) {
      facc4 v = acc[ml][nt];
      int n = nt * 16 + nlo, mb = (mt0 + ml) * 16 + quad * 4;
#pragma unroll
      for (int r = 0; r < 4; ++r)
        C2[(unsigned)bi * 4096u + (mb + r) * 32 + n] = f2bf(v[r]);
    }
}

// ---------- transpose 1: C2[bi][m][n] -> X2m[mode][b][ic] ----------
__global__ void k_t1(unsigned short* ws) {
  const unsigned short* C2 = ws + C2_O;
  unsigned short* X2m = ws + X2M_O;
  int mode = blockIdx.x, ky = mode >> 5, kx = mode & 31;
  int t = threadIdx.x, b = t >> 4, icb = (t & 15) * 8;
  unsigned short outv[8];
#pragma unroll
  for (int e = 0; e < 8; ++e) {
    int ic = icb + e, i = ic & 63, half = ic >> 6;
    outv[e] = C2[(unsigned)(b * 64 + i) * 4096u + (half * 63 + ky) * 32 + kx];
  }
  *(uint4*)(X2m + (unsigned)mode * 2048u + b * 128 + icb) = *(uint4*)outv;
}

// ---------- stage 3: mode mix.  C3 = X2m[mode] (16x128) * Wf[mode] (128x128) ----------
__global__ void k_s3(unsigned short* ws) {
  const unsigned short* X2m = ws + X2M_O;
  const unsigned short* Wf = ws + WF_O;
  unsigned short* C3 = ws + C3_O;
  int t = threadIdx.x, lane = t & 63, w = t >> 6, quad = lane >> 4, nlo = lane & 15;
  int nt0 = w * 2;
  for (int mm = 0; mm < 8; ++mm) {
    int mode = blockIdx.x * 8 + mm;
    facc4 acc0 = (facc4){0.f, 0.f, 0.f, 0.f}, acc1 = acc0;
    const unsigned short* Am = X2m + (unsigned)mode * 2048u;
    const unsigned short* Bm = Wf + (unsigned)mode * 16384u;
#pragma unroll
    for (int ks = 0; ks < 4; ++ks) {
      bfrag8 a = ldf(Am + nlo * 128 + ks * 32 + quad * 8);
      bfrag8 b0 = ldf(Bm + ((ks * 8 + nt0) * 64 + lane) * 8);
      bfrag8 b1 = ldf(Bm + ((ks * 8 + nt0 + 1) * 64 + lane) * 8);
      acc0 = __builtin_amdgcn_mfma_f32_16x16x32_bf16(a, b0, acc0, 0, 0, 0);
      acc1 = __builtin_amdgcn_mfma_f32_16x16x32_bf16(a, b1, acc1, 0, 0, 0);
    }
    int bq = quad * 4;
#pragma unroll
    for (int r = 0; r < 4; ++r) {
      C3[(unsigned)mode * 2048u + (bq + r) * 128 + nt0 * 16 + nlo] = f2bf(acc0[r]);
      C3[(unsigned)mode * 2048u + (bq + r) * 128 + (nt0 + 1) * 16 + nlo] = f2bf(acc1[r]);
    }
  }
}

// ---------- transpose 2: C3[mode][b][nc] -> X3t[bo][kx][kk] ----------
__global__ void k_t2(unsigned short* ws) {
  const unsigned short* C3 = ws + C3_O;
  unsigned short* X3t = ws + X3T_O;
  int bo = blockIdx.x, b = bo >> 6, o = bo & 63;
  int t = threadIdx.x, kx = t >> 3, kkb = (t & 7) * 16;
  unsigned short outv[16];
#pragma unroll
  for (int e = 0; e < 16; ++e) {
    int kk = kkb + e;
    unsigned short v = 0;
    if (kk < 63)        v = C3[(unsigned)(kk * 32 + kx) * 2048u + b * 128 + o];
    else if (kk < 126)  v = C3[(unsigned)((kk - 63) * 32 + kx) * 2048u + b * 128 + 64 + o];
    outv[e] = v;
  }
  *(uint4*)(X3t + (unsigned)bo * 4096u + kx * 128 + kkb) = *(uint4*)outv;
  *(uint4*)(X3t + (unsigned)bo * 4096u + kx * 128 + kkb + 8) = *(uint4*)(outv + 8);
}

// ---------- stage 4: col iDFT.  Y1 = T4 (512x128) * X3t[bo] (128x32) ----------
__global__ void k_s4(unsigned short* ws) {
  const unsigned short* T4f = ws + T4F_O;
  const unsigned short* X3t = ws + X3T_O;
  unsigned short* Y1 = ws + Y1_O;
  int t = threadIdx.x, lane = t & 63, w = t >> 6, quad = lane >> 4, nlo = lane & 15;
  int bo = blockIdx.x, mt0 = w * 8;
  facc4 acc[8][2];
#pragma unroll
  for (int a = 0; a < 8; ++a)
#pragma unroll
    for (int b = 0; b < 2; ++b) acc[a][b] = (facc4){0.f, 0.f, 0.f, 0.f};
  const unsigned short* Bb = X3t + (unsigned)bo * 4096u;
#pragma unroll
  for (int ks = 0; ks < 4; ++ks) {
    bfrag8 b0 = ldf(Bb + nlo * 128 + ks * 32 + quad * 8);
    bfrag8 b1 = ldf(Bb + (16 + nlo) * 128 + ks * 32 + quad * 8);
#pragma unroll
    for (int ml = 0; ml < 8; ++ml) {
      bfrag8 a = ldf(T4f + (((mt0 + ml) * 4 + ks) * 64 + lane) * 8);
      acc[ml][0] = __builtin_amdgcn_mfma_f32_16x16x32_bf16(a, b0, acc[ml][0], 0, 0, 0);
      acc[ml][1] = __builtin_amdgcn_mfma_f32_16x16x32_bf16(a, b1, acc[ml][1], 0, 0, 0);
    }
  }
#pragma unroll
  for (int ml = 0; ml < 8; ++ml)
#pragma unroll
    for (int nt = 0; nt < 2; ++nt) {
      facc4 v = acc[ml][nt];
      int m = (mt0 + ml) * 16 + quad * 4, n = nt * 16 + nlo;
#pragma unroll
      for (int r = 0; r < 4; ++r)
        Y1[(unsigned)bo * 16384u + (m + r) * 32 + n] = f2bf(v[r]);
    }
}

// ---------- stage 5: row irDFT.  out = Y1-rows (128x64) * F5 (64x256) ----------
__global__ void k_s5(unsigned short* ws, float* __restrict__ out) {
  __shared__ unsigned short F5s[16384];
  const unsigned short* F5g = ws + F5F_O;
  const unsigned short* Y1 = ws + Y1_O;
  int t = threadIdx.x;
#pragma unroll
  for (int q = 0; q < 8; ++q)
    ((uint4*)F5s)[q * 256 + t] = ((const uint4*)F5g)[q * 256 + t];
  __syncthreads();
  int lane = t & 63, w = t >> 6, quad = lane >> 4, nlo = lane & 15;
  int mblk = blockIdx.x >> 1, nh = blockIdx.x & 1;
  int bo = mblk >> 1, y0 = (mblk & 1) * 128, x0 = nh * 128;
  int mt0 = w * 2;
  facc4 acc[2][8];
#pragma unroll
  for (int a = 0; a < 2; ++a)
#pragma unroll
    for (int b = 0; b < 8; ++b) acc[a][b] = (facc4){0.f, 0.f, 0.f, 0.f};
  const unsigned short* Yb = Y1 + (unsigned)bo * 16384u;
#pragma unroll
  for (int ks = 0; ks < 2; ++ks) {
    bfrag8 a0 = ldf(Yb + (ks * 256 + y0 + mt0 * 16 + nlo) * 32 + quad * 8);
    bfrag8 a1 = ldf(Yb + (ks * 256 + y0 + (mt0 + 1) * 16 + nlo) * 32 + quad * 8);
#pragma unroll
    for (int nt = 0; nt < 8; ++nt) {
      bfrag8 b = *(bfrag8*)(F5s + ((ks * 16 + nh * 8 + nt) * 64 + lane) * 8);
      acc[0][nt] = __builtin_amdgcn_mfma_f32_16x16x32_bf16(a0, b, acc[0][nt], 0, 0, 0);
      acc[1][nt] = __builtin_amdgcn_mfma_f32_16x16x32_bf16(a1, b, acc[1][nt], 0, 0, 0);
    }
  }
  float* ob = out + (size_t)bo * 65536 + (size_t)y0 * 256 + x0;
#pragma unroll
  for (int ml = 0; ml < 2; ++ml)
#pragma unroll
    for (int nt = 0; nt < 8; ++nt) {
      int yr = (mt0 + ml) * 16 + quad * 4, xc = nt * 16 + nlo;
      facc4 v = acc[ml][nt];
#pragma unroll
      for (int r = 0; r < 4; ++r) ob[(yr + r) * 256 + xc] = v[r];
    }
}

extern "C" void kernel_launch(void* const* d_in, const int* in_sizes, int n_in,
                              void* d_out, int out_size, void* d_ws, size_t ws_size,
                              hipStream_t stream) {
  (void)in_sizes; (void)n_in; (void)out_size; (void)ws_size;
  const float* x   = (const float*)d_in[0];
  const float* y0r = (const float*)d_in[1];
  const float* y0i = (const float*)d_in[2];
  const float* ypr = (const float*)d_in[3];
  const float* ypi = (const float*)d_in[4];
  const float* w00 = (const float*)d_in[5];
  unsigned short* ws = (unsigned short*)d_ws;
  float* out = (float*)d_out;

  k_tables<<<dim3(160),  dim3(256), 0, stream>>>(ws);
  k_wf    <<<dim3(2016), dim3(256), 0, stream>>>(y0r, y0i, ypr, ypi, w00, ws);
  k_s1    <<<dim3(2048), dim3(256), 0, stream>>>(x, ws);
  k_s2    <<<dim3(1024), dim3(256), 0, stream>>>(ws);
  k_t1    <<<dim3(2016), dim3(256), 0, stream>>>(ws);
  k_s3    <<<dim3(252),  dim3(256), 0, stream>>>(ws);
  k_t2    <<<dim3(1024), dim3(256), 0, stream>>>(ws);
  k_s4    <<<dim3(1024), dim3(256), 0, stream>>>(ws);
  k_s5    <<<dim3(4096), dim3(256), 0, stream>>>(ws, out);
}

// Round 2
// 624.618 us; speedup vs baseline: 1.5803x; 1.5803x over previous
//
#include <hip/hip_runtime.h>

// SpectralConv2d as 5 bf16-MFMA GEMM stages + coalesced table/weight builds + 2 LDS-tiled transposes.
// B=16, Ci=Co=64, S=256, m1=m2=32 -> 63x32 retained modes.

typedef __attribute__((ext_vector_type(8))) short bfrag8;   // 8 bf16 = 16B
typedef __attribute__((ext_vector_type(4))) float facc4;    // MFMA accumulator

// ---- workspace layout (bf16-element offsets) ----
#define F1F_O 0u            // [8 ks][4 nt][64 lane][8 j]        16384
#define T2F_O 16384u        // [8 mt][16 ks][64][8]              65536
#define T4F_O 81920u        // [32 mt][4 ks][64][8]              65536
#define F5F_O 147456u       // [2 ks][16 nt][64][8]              16384
#define WF_O  163840u       // [2016 mode][4 ks][8 nt][64][8]    33030144
#define X1T_O 33193984u     // [1024 bi][32 n][512 kk]           16777216
#define C2_O  49971200u     // [1024 bi][128 m][32 n]            4194304
#define X2M_O 54165504u     // [2016 mode][16 b][128 ic]         4128768
// overlays (stream-ordered lifetimes):
#define WTMP_O X1T_O                  // uint[2016 mode][4096 io] (r|i<<16), dead before s1
#define Y1_O  WF_O                    // [1024 bo][512 m][32 n] after s3
#define C3_O  X1T_O                   // [2016 mode][16 b][128 nc] after s2
#define X3T_O (X1T_O + 4128768u)      // [1024 bo][32 kx][128 kk]

#define TWO_PI_256 0.0245436926f

__device__ __forceinline__ unsigned short f2bf(float f) {
  unsigned u = __float_as_uint(f);
  u += 0x7fffu + ((u >> 16) & 1u);          // RNE
  return (unsigned short)(u >> 16);
}
__device__ __forceinline__ bfrag8 ldf(const unsigned short* p) {
  return *(const bfrag8*)p;
}

// ---------- build constant DFT matrices in fragment-linear layout ----------
__global__ void k_tables(unsigned short* ws) {
  int t = threadIdx.x;
  for (int q = 0; q < 4; ++q) {
    int idx = blockIdx.x * 1024 + q * 256 + t;
    float val = 0.f; unsigned dst;
    if (idx < 16384) {                       // F1f: B[k=x][n], fwd row rDFT, /256
      int u = idx, j = u & 7, lane = (u >> 3) & 63, nt = (u >> 9) & 3, ks = u >> 11;
      int k = ks * 32 + (lane >> 4) * 8 + j, n = nt * 16 + (lane & 15);
      if (n < 32) val =  cosf((float)((k * n) & 255) * TWO_PI_256) * (1.f / 256.f);
      else        val = -sinf((float)((k * (n - 32)) & 255) * TWO_PI_256) * (1.f / 256.f);
      dst = F1F_O + (unsigned)idx;
    } else if (idx < 81920) {                // T2f: A[m][kk], fwd col DFT (real form)
      int u = idx - 16384, j = u & 7, lane = (u >> 3) & 63, ks = (u >> 9) & 15, mt = u >> 13;
      int m = mt * 16 + (lane & 15), k = ks * 32 + (lane >> 4) * 8 + j;
      if (m < 126) {
        int ky = m < 63 ? m : m - 63;
        int y = k & 255, f = (ky + 225) & 255;
        float ang = (float)((y * f) & 255) * TWO_PI_256;
        float c = cosf(ang), s = sinf(ang);
        val = (m < 63) ? ((k < 256) ? c : s) : ((k < 256) ? -s : c);
      }
      dst = T2F_O + (unsigned)u;
    } else if (idx < 147456) {               // T4f: A[m][kk], inv col DFT
      int u = idx - 81920, j = u & 7, lane = (u >> 3) & 63, ks = (u >> 9) & 3, mt = u >> 11;
      int m = mt * 16 + (lane & 15), k = ks * 32 + (lane >> 4) * 8 + j;
      if (k < 126) {
        int ky = k < 63 ? k : k - 63;
        int y = m & 255, f = (ky + 225) & 255;
        float ang = (float)((y * f) & 255) * TWO_PI_256;
        float c = cosf(ang), s = sinf(ang);
        val = (m < 256) ? ((k < 63) ? c : -s) : ((k < 63) ? s : c);
      }
      dst = T4F_O + (unsigned)u;
    } else {                                 // F5f: B[k][n=x], inv row irDFT, /256
      int u = idx - 147456, j = u & 7, lane = (u >> 3) & 63, nt = (u >> 9) & 15, ks = u >> 13;
      int k = ks * 32 + (lane >> 4) * 8 + j, n = nt * 16 + (lane & 15);
      int kf = k & 31;
      float ang = (float)((kf * n) & 255) * TWO_PI_256;
      if (k < 32) val = ((kf == 0) ? 1.f : 2.f) * cosf(ang) * (1.f / 256.f);
      else        val = (kf == 0) ? 0.f : -2.f * sinf(ang) * (1.f / 256.f);
      dst = F5F_O + (unsigned)u;
    }
    ws[dst] = f2bf(val);
  }
}

// ---------- weight build pass A: coalesced read -> Wtmp[mode][io] packed (r,i) ----------
// block: 16 io-chunks x 16 ky-quads. Thread owns io, reads 124 contiguous floats per array.
__global__ void k_wpre(const float* __restrict__ y0r, const float* __restrict__ y0i,
                       const float* __restrict__ ypr, const float* __restrict__ ypi,
                       const float* __restrict__ w00, unsigned short* ws) {
  unsigned* Wtmp = (unsigned*)(ws + WTMP_O);
  int chunk = blockIdx.x >> 4, kq = blockIdx.x & 15;
  int io = chunk * 256 + threadIdx.x;
  int ky0 = kq * 4, nky = (kq == 15) ? 3 : 4;
  const float* pr = ypr + (size_t)io * 1953 + (size_t)ky0 * 31;
  const float* pi_ = ypi + (size_t)io * 1953 + (size_t)ky0 * 31;
  for (int q = 0; q < nky; ++q) {
    int ky = ky0 + q;
#pragma unroll
    for (int kxs = 0; kxs < 31; ++kxs) {
      float r = pr[q * 31 + kxs], im = pi_[q * 31 + kxs];
      Wtmp[(unsigned)(ky * 32 + kxs + 1) * 4096u + io] =
          (unsigned)f2bf(r) | ((unsigned)f2bf(im) << 16);
    }
  }
  if (kq == 0) {                             // col0: y0 / w00 / conj(flip(y0))
    float rr[31], ii[31];
#pragma unroll
    for (int j = 0; j < 31; ++j) { rr[j] = y0r[io * 31 + j]; ii[j] = y0i[io * 31 + j]; }
    float w0 = w00[io];
    for (int ky = 0; ky < 63; ++ky) {
      float r, im;
      if (ky < 31)       { r = rr[ky];      im = ii[ky]; }
      else if (ky == 31) { r = w0;          im = 0.f; }
      else               { r = rr[62 - ky]; im = -ii[62 - ky]; }
      Wtmp[(unsigned)(ky * 32) * 4096u + io] =
          (unsigned)f2bf(r) | ((unsigned)f2bf(im) << 16);
    }
  }
}

// ---------- weight build pass B: expand quadrants, write Wf frag-linear ----------
__global__ void k_wexp(unsigned short* ws) {
  __shared__ unsigned lds[64 * 65];          // [i][o] pad 64->65: conflict-free
  const unsigned* Wtmp = (const unsigned*)(ws + WTMP_O);
  unsigned short* Wf = ws + WF_O;
  int mode = blockIdx.x, t = threadIdx.x;
#pragma unroll
  for (int q = 0; q < 4; ++q) {
    int io = q * 1024 + t * 4;
    uint4 v = *(const uint4*)(Wtmp + (unsigned)mode * 4096u + io);
    unsigned base = (unsigned)(io >> 6) * 65u + (io & 63);
    lds[base] = v.x; lds[base + 1] = v.y; lds[base + 2] = v.z; lds[base + 3] = v.w;
  }
  __syncthreads();
#pragma unroll
  for (int c = 0; c < 8; ++c) {
    int hi = c * 256 + t;
    int lane = hi & 63, nt = (hi >> 6) & 7, ks = hi >> 9;
    int quad = lane >> 4, nlo = lane & 15;
    int n = nt * 16 + nlo, o = n & 63, oh = n >> 6;
    unsigned short outv[8];
#pragma unroll
    for (int j = 0; j < 8; ++j) {
      int k = ks * 32 + quad * 8 + j, i = k & 63, kh = k >> 6;
      unsigned pk = lds[i * 65 + o];
      unsigned short r = (unsigned short)(pk & 0xffffu);
      unsigned short im = (unsigned short)(pk >> 16);
      outv[j] = (kh == 0) ? ((oh == 0) ? r : im)
                          : ((oh == 0) ? (unsigned short)(im ^ 0x8000u) : r);
    }
    *(uint4*)(Wf + (unsigned)mode * 16384u + hi * 8) = *(uint4*)outv;
  }
}

// ---------- stage 1: row rDFT.  C1 = bf16(x) (128x256) * F1 (256x64) -> X1t ----------
__global__ void k_s1(const float* __restrict__ x, unsigned short* ws) {
  __shared__ unsigned short F1s[16384];
  __shared__ unsigned short As[128 * 40];     // pad 32->40 (16B-aligned rows, conflict-free)
  const unsigned short* F1g = ws + F1F_O;
  unsigned short* X1t = ws + X1T_O;
  int t = threadIdx.x;
  int bi = blockIdx.x >> 1, y0 = (blockIdx.x & 1) * 128;
#pragma unroll
  for (int q = 0; q < 8; ++q)
    ((uint4*)F1s)[q * 256 + t] = ((const uint4*)F1g)[q * 256 + t];
  int lane = t & 63, w = t >> 6, quad = lane >> 4, nlo = lane & 15;
  int mt0 = w * 2;
  facc4 acc[2][4];
#pragma unroll
  for (int a = 0; a < 2; ++a)
#pragma unroll
    for (int b = 0; b < 4; ++b) acc[a][b] = (facc4){0.f, 0.f, 0.f, 0.f};
  const float* img = x + (size_t)bi * 65536 + (size_t)y0 * 256;
  for (int ks = 0; ks < 8; ++ks) {
    __syncthreads();
#pragma unroll
    for (int q = 0; q < 4; ++q) {             // stage 128x32 fp32 -> bf16 LDS
      int flat = q * 1024 + t * 4;
      int r = flat >> 5, cc = flat & 31;
      float4 v = *(const float4*)(img + r * 256 + ks * 32 + cc);
      unsigned short b4[4] = { f2bf(v.x), f2bf(v.y), f2bf(v.z), f2bf(v.w) };
      *(uint2*)(As + r * 40 + cc) = *(uint2*)b4;
    }
    __syncthreads();
    bfrag8 a0 = *(bfrag8*)(As + (mt0 * 16 + nlo) * 40 + quad * 8);
    bfrag8 a1 = *(bfrag8*)(As + ((mt0 + 1) * 16 + nlo) * 40 + quad * 8);
#pragma unroll
    for (int nt = 0; nt < 4; ++nt) {
      bfrag8 b = *(bfrag8*)(F1s + ((ks * 4 + nt) * 64 + lane) * 8);
      acc[0][nt] = __builtin_amdgcn_mfma_f32_16x16x32_bf16(a0, b, acc[0][nt], 0, 0, 0);
      acc[1][nt] = __builtin_amdgcn_mfma_f32_16x16x32_bf16(a1, b, acc[1][nt], 0, 0, 0);
    }
  }
#pragma unroll
  for (int ml = 0; ml < 2; ++ml)
#pragma unroll
    for (int nt = 0; nt < 4; ++nt) {
      facc4 v = acc[ml][nt];
      int ccol = nt * 16 + nlo, n = ccol & 31, half = ccol >> 5;
      int yrow = y0 + (mt0 + ml) * 16 + quad * 4;
      unsigned short pk[4] = { f2bf(v[0]), f2bf(v[1]), f2bf(v[2]), f2bf(v[3]) };
      *(uint2*)(X1t + (unsigned)bi * 16384u + n * 512 + half * 256 + yrow) = *(uint2*)pk;
    }
}

// ---------- stage 2: col DFT.  C2 = T2 (128x512) * X1t[bi] (512x32) ----------
__global__ void k_s2(unsigned short* ws) {
  const unsigned short* T2f = ws + T2F_O;
  const unsigned short* X1t = ws + X1T_O;
  unsigned short* C2 = ws + C2_O;
  int t = threadIdx.x, lane = t & 63, w = t >> 6, quad = lane >> 4, nlo = lane & 15;
  int bi = blockIdx.x, mt0 = w * 2;
  facc4 acc[2][2];
#pragma unroll
  for (int a = 0; a < 2; ++a)
#pragma unroll
    for (int b = 0; b < 2; ++b) acc[a][b] = (facc4){0.f, 0.f, 0.f, 0.f};
  const unsigned short* Bb = X1t + (unsigned)bi * 16384u;
  for (int ks = 0; ks < 16; ++ks) {
    bfrag8 a0 = ldf(T2f + ((mt0 * 16 + ks) * 64 + lane) * 8);
    bfrag8 a1 = ldf(T2f + (((mt0 + 1) * 16 + ks) * 64 + lane) * 8);
    bfrag8 b0 = ldf(Bb + nlo * 512 + ks * 32 + quad * 8);
    bfrag8 b1 = ldf(Bb + (16 + nlo) * 512 + ks * 32 + quad * 8);
    acc[0][0] = __builtin_amdgcn_mfma_f32_16x16x32_bf16(a0, b0, acc[0][0], 0, 0, 0);
    acc[0][1] = __builtin_amdgcn_mfma_f32_16x16x32_bf16(a0, b1, acc[0][1], 0, 0, 0);
    acc[1][0] = __builtin_amdgcn_mfma_f32_16x16x32_bf16(a1, b0, acc[1][0], 0, 0, 0);
    acc[1][1] = __builtin_amdgcn_mfma_f32_16x16x32_bf16(a1, b1, acc[1][1], 0, 0, 0);
  }
#pragma unroll
  for (int ml = 0; ml < 2; ++ml)
#pragma unroll
    for (int nt = 0; nt < 2; ++nt) {
      facc4 v = acc[ml][nt];
      int n = nt * 16 + nlo, mb = (mt0 + ml) * 16 + quad * 4;
#pragma unroll
      for (int r = 0; r < 4; ++r)
        C2[(unsigned)bi * 4096u + (mb + r) * 32 + n] = f2bf(v[r]);
    }
}

// ---------- transpose 1 (LDS-tiled): C2[bi][m][n] -> X2m[mode][b][ic] ----------
// block: (ky, b-range of 4). Stage rows coalesced, write uint4 coalesced.
__global__ void k_t1(unsigned short* ws) {
  __shared__ unsigned short lds[512 * 36];    // [half(2)][bloc(4)][i(64)] rows x 32 kx, pad 36
  const unsigned short* C2 = ws + C2_O;
  unsigned short* X2m = ws + X2M_O;
  int ky = blockIdx.x >> 2, b0 = (blockIdx.x & 3) * 4;
  int t = threadIdx.x;
#pragma unroll
  for (int rr = 0; rr < 2; ++rr) {
    int R = rr * 256 + t;
    int half = R >> 8, bloc = (R >> 6) & 3, i = R & 63;
    const uint2* src2 = (const uint2*)(C2 + (unsigned)((b0 + bloc) * 64 + i) * 4096u
                                          + (half * 63 + ky) * 32);
    uint2* d2 = (uint2*)(lds + R * 36);
#pragma unroll
    for (int c = 0; c < 8; ++c) d2[c] = src2[c];
  }
  __syncthreads();
#pragma unroll
  for (int it = 0; it < 8; ++it) {
    int flat = (it * 256 + t) * 8;            // [kx(32)][bloc(4)][ic(128)]
    int kx = flat >> 9, bloc = (flat >> 7) & 3, ic0 = flat & 127;
    unsigned short outv[8];
#pragma unroll
    for (int j = 0; j < 8; ++j) {
      int ic = ic0 + j, i = ic & 63, half = ic >> 6;
      outv[j] = lds[(half * 256 + bloc * 64 + i) * 36 + kx];
    }
    *(uint4*)(X2m + (unsigned)(ky * 32 + kx) * 2048u + (b0 + bloc) * 128 + ic0) = *(uint4*)outv;
  }
}

// ---------- stage 3: mode mix.  C3 = X2m[mode] (16x128) * Wf[mode] (128x128) ----------
__global__ void k_s3(unsigned short* ws) {
  const unsigned short* X2m = ws + X2M_O;
  const unsigned short* Wf = ws + WF_O;
  unsigned short* C3 = ws + C3_O;
  int t = threadIdx.x, lane = t & 63, w = t >> 6, quad = lane >> 4, nlo = lane & 15;
  int nt0 = w * 2;
  for (int mm = 0; mm < 8; ++mm) {
    int mode = blockIdx.x * 8 + mm;
    facc4 acc0 = (facc4){0.f, 0.f, 0.f, 0.f}, acc1 = acc0;
    const unsigned short* Am = X2m + (unsigned)mode * 2048u;
    const unsigned short* Bm = Wf + (unsigned)mode * 16384u;
#pragma unroll
    for (int ks = 0; ks < 4; ++ks) {
      bfrag8 a = ldf(Am + nlo * 128 + ks * 32 + quad * 8);
      bfrag8 b0 = ldf(Bm + ((ks * 8 + nt0) * 64 + lane) * 8);
      bfrag8 b1 = ldf(Bm + ((ks * 8 + nt0 + 1) * 64 + lane) * 8);
      acc0 = __builtin_amdgcn_mfma_f32_16x16x32_bf16(a, b0, acc0, 0, 0, 0);
      acc1 = __builtin_amdgcn_mfma_f32_16x16x32_bf16(a, b1, acc1, 0, 0, 0);
    }
    int bq = quad * 4;
#pragma unroll
    for (int r = 0; r < 4; ++r) {
      C3[(unsigned)mode * 2048u + (bq + r) * 128 + nt0 * 16 + nlo] = f2bf(acc0[r]);
      C3[(unsigned)mode * 2048u + (bq + r) * 128 + (nt0 + 1) * 16 + nlo] = f2bf(acc1[r]);
    }
  }
}

// ---------- transpose 2 (LDS-tiled): C3[mode][b][nc] -> X3t[bo][kx][kk] ----------
// block: (kx, b-range of 2). Stage 1KB runs coalesced, write uint4 coalesced.
__global__ void k_t2(unsigned short* ws) {
  __shared__ unsigned short lds[2 * 63 * 132]; // [bloc(2)][ky(63)] rows x 128 nc, pad 132
  const unsigned short* C3 = ws + C3_O;
  unsigned short* X3t = ws + X3T_O;
  int kx = blockIdx.x >> 3, b0 = (blockIdx.x & 7) * 2;
  int t = threadIdx.x;
#pragma unroll
  for (int it = 0; it < 8; ++it) {
    int g = it * 256 + t;
    if (g < 2016) {
      int flat = g * 8;                       // [ky(63)][bloc(2)][nc(128)]
      int ky = flat >> 8, bloc = (flat >> 7) & 1, nc0 = flat & 127;
      const uint2* src2 = (const uint2*)(C3 + (unsigned)(ky * 32 + kx) * 2048u
                                            + (b0 + bloc) * 128 + nc0);
      uint2* d2 = (uint2*)(lds + (bloc * 63 + ky) * 132 + nc0);
      d2[0] = src2[0]; d2[1] = src2[1];
    }
  }
  __syncthreads();
#pragma unroll
  for (int it = 0; it < 8; ++it) {
    int flat = (it * 256 + t) * 8;            // [bloc(2)][o(64)][kk(128)]
    int bloc = flat >> 13, o = (flat >> 7) & 63, kk0 = flat & 127;
    unsigned short outv[8];
#pragma unroll
    for (int j = 0; j < 8; ++j) {
      int kk = kk0 + j;
      unsigned short v = 0;
      if (kk < 63)        v = lds[(bloc * 63 + kk) * 132 + o];
      else if (kk < 126)  v = lds[(bloc * 63 + (kk - 63)) * 132 + 64 + o];
      outv[j] = v;
    }
    int bo = (b0 + bloc) * 64 + o;
    *(uint4*)(X3t + (unsigned)bo * 4096u + kx * 128 + kk0) = *(uint4*)outv;
  }
}

// ---------- stage 4: col iDFT.  Y1 = T4 (512x128) * X3t[bo] (128x32) ----------
__global__ void k_s4(unsigned short* ws) {
  const unsigned short* T4f = ws + T4F_O;
  const unsigned short* X3t = ws + X3T_O;
  unsigned short* Y1 = ws + Y1_O;
  int t = threadIdx.x, lane = t & 63, w = t >> 6, quad = lane >> 4, nlo = lane & 15;
  int bo = blockIdx.x, mt0 = w * 8;
  facc4 acc[8][2];
#pragma unroll
  for (int a = 0; a < 8; ++a)
#pragma unroll
    for (int b = 0; b < 2; ++b) acc[a][b] = (facc4){0.f, 0.f, 0.f, 0.f};
  const unsigned short* Bb = X3t + (unsigned)bo * 4096u;
#pragma unroll
  for (int ks = 0; ks < 4; ++ks) {
    bfrag8 b0 = ldf(Bb + nlo * 128 + ks * 32 + quad * 8);
    bfrag8 b1 = ldf(Bb + (16 + nlo) * 128 + ks * 32 + quad * 8);
#pragma unroll
    for (int ml = 0; ml < 8; ++ml) {
      bfrag8 a = ldf(T4f + (((mt0 + ml) * 4 + ks) * 64 + lane) * 8);
      acc[ml][0] = __builtin_amdgcn_mfma_f32_16x16x32_bf16(a, b0, acc[ml][0], 0, 0, 0);
      acc[ml][1] = __builtin_amdgcn_mfma_f32_16x16x32_bf16(a, b1, acc[ml][1], 0, 0, 0);
    }
  }
#pragma unroll
  for (int ml = 0; ml < 8; ++ml)
#pragma unroll
    for (int nt = 0; nt < 2; ++nt) {
      facc4 v = acc[ml][nt];
      int m = (mt0 + ml) * 16 + quad * 4, n = nt * 16 + nlo;
#pragma unroll
      for (int r = 0; r < 4; ++r)
        Y1[(unsigned)bo * 16384u + (m + r) * 32 + n] = f2bf(v[r]);
    }
}

// ---------- stage 5: row irDFT.  out = Y1-rows (128x64) * F5 (64x256) ----------
__global__ void k_s5(unsigned short* ws, float* __restrict__ out) {
  __shared__ unsigned short F5s[16384];
  const unsigned short* F5g = ws + F5F_O;
  const unsigned short* Y1 = ws + Y1_O;
  int t = threadIdx.x;
#pragma unroll
  for (int q = 0; q < 8; ++q)
    ((uint4*)F5s)[q * 256 + t] = ((const uint4*)F5g)[q * 256 + t];
  __syncthreads();
  int lane = t & 63, w = t >> 6, quad = lane >> 4, nlo = lane & 15;
  int mblk = blockIdx.x >> 1, nh = blockIdx.x & 1;
  int bo = mblk >> 1, y0 = (mblk & 1) * 128, x0 = nh * 128;
  int mt0 = w * 2;
  facc4 acc[2][8];
#pragma unroll
  for (int a = 0; a < 2; ++a)
#pragma unroll
    for (int b = 0; b < 8; ++b) acc[a][b] = (facc4){0.f, 0.f, 0.f, 0.f};
  const unsigned short* Yb = Y1 + (unsigned)bo * 16384u;
#pragma unroll
  for (int ks = 0; ks < 2; ++ks) {
    bfrag8 a0 = ldf(Yb + (ks * 256 + y0 + mt0 * 16 + nlo) * 32 + quad * 8);
    bfrag8 a1 = ldf(Yb + (ks * 256 + y0 + (mt0 + 1) * 16 + nlo) * 32 + quad * 8);
#pragma unroll
    for (int nt = 0; nt < 8; ++nt) {
      bfrag8 b = *(bfrag8*)(F5s + ((ks * 16 + nh * 8 + nt) * 64 + lane) * 8);
      acc[0][nt] = __builtin_amdgcn_mfma_f32_16x16x32_bf16(a0, b, acc[0][nt], 0, 0, 0);
      acc[1][nt] = __builtin_amdgcn_mfma_f32_16x16x32_bf16(a1, b, acc[1][nt], 0, 0, 0);
    }
  }
  float* ob = out + (size_t)bo * 65536 + (size_t)y0 * 256 + x0;
#pragma unroll
  for (int ml = 0; ml < 2; ++ml)
#pragma unroll
    for (int nt = 0; nt < 8; ++nt) {
      int yr = (mt0 + ml) * 16 + quad * 4, xc = nt * 16 + nlo;
      facc4 v = acc[ml][nt];
#pragma unroll
      for (int r = 0; r < 4; ++r) ob[(yr + r) * 256 + xc] = v[r];
    }
}

extern "C" void kernel_launch(void* const* d_in, const int* in_sizes, int n_in,
                              void* d_out, int out_size, void* d_ws, size_t ws_size,
                              hipStream_t stream) {
  (void)in_sizes; (void)n_in; (void)out_size; (void)ws_size;
  const float* x   = (const float*)d_in[0];
  const float* y0r = (const float*)d_in[1];
  const float* y0i = (const float*)d_in[2];
  const float* ypr = (const float*)d_in[3];
  const float* ypi = (const float*)d_in[4];
  const float* w00 = (const float*)d_in[5];
  unsigned short* ws = (unsigned short*)d_ws;
  float* out = (float*)d_out;

  k_tables<<<dim3(160),  dim3(256), 0, stream>>>(ws);
  k_wpre  <<<dim3(256),  dim3(256), 0, stream>>>(y0r, y0i, ypr, ypi, w00, ws);
  k_wexp  <<<dim3(2016), dim3(256), 0, stream>>>(ws);
  k_s1    <<<dim3(2048), dim3(256), 0, stream>>>(x, ws);
  k_s2    <<<dim3(1024), dim3(256), 0, stream>>>(ws);
  k_t1    <<<dim3(252),  dim3(256), 0, stream>>>(ws);
  k_s3    <<<dim3(252),  dim3(256), 0, stream>>>(ws);
  k_t2    <<<dim3(256),  dim3(256), 0, stream>>>(ws);
  k_s4    <<<dim3(1024), dim3(256), 0, stream>>>(ws);
  k_s5    <<<dim3(4096), dim3(256), 0, stream>>>(ws, out);
}